// Round 19
// baseline (79.217 us; speedup 1.0000x reference)
//
#include <hip/hip_runtime.h>

// Problem constants (fixed by the reference)
#define NB    8
#define NPTS  4096
#define KNN   16
#define CG    16          // coarse cells per axis; cell = 0.0625
#define NCC   (CG * CG)   // 256 cells per batch
#define PCAP  16          // passers/query: avg 1.4, Poisson P(>16)~1e-12;
                          // prior rounds (PCAP 24) never exceeded 16.

// r^2 exactly as the reference: RADIUS = 5.0/480 in f64, squared in f64,
// rounded to f32 by weak promotion in `d2 < radius*radius`.
#define R2F ((float)((5.0 / 480.0) * (5.0 / 480.0)))
#define WIN 0.011f

typedef short short8 __attribute__((ext_vector_type(8)));
typedef float f32x4 __attribute__((ext_vector_type(4)));

// f32 -> bf16 round-to-nearest-even (top 16 bits after rounding).
static __device__ __forceinline__ unsigned short f2bf(float f) {
  unsigned u = __float_as_uint(f);
  u += 0x7FFFu + ((u >> 16) & 1u);
  return (unsigned short)(u >> 16);
}

// ---------------------------------------------------------------------------
// K_all: R18 champion (76.84us, absmax 6.1e-5, payload 14.2us) with the
// build redundancy halved: 256 blocks x 128 queries (was 512 x 64). The
// build (8192 LDS atomics + scatter, ~4-5us, 64x redundant per batch) was
// the largest controllable term; now 256 builds instead of 512, and the
// launch ramp halves (4096 fewer waves). Per-query math is byte-identical
// to R18 -> absmax must stay exactly 6.103516e-05.
// LDS rebudget (64.0KB): csrXY as float2 (1 b64 op where build/scan/ph3
// used 2 b32); embT stored bf16 (f2bf moved from ph4-read to ph3-write,
// same bits); plist PCAP 16. ph3 completes all 128 queries BEFORE hs16b
// overlays csrXY; then two 64-query MFMA chunks (R18's ph4/ph5 + column
// offset).
// Fragment layouts (gfx950 16x16x32 bf16): A[l&15][(l>>4)*8+i],
// B[(l>>4)*8+i][l&15], D col=l&15 row=(l>>4)*4+j (guide m89-verified).
// ---------------------------------------------------------------------------
__global__ __launch_bounds__(1024, 8) void k_all(
    const float4* __restrict__ xytp4, const float* __restrict__ W1,
    const float* __restrict__ b1, const float* __restrict__ W2,
    const float* __restrict__ b2, float* __restrict__ out) {
#pragma clang fp contract(off)
  // Region A (32KB): csrXY[4096] float2 -> hs16b[64][136] after ph3.
  __shared__ __align__(16) char smemA[32768];
  __shared__ unsigned short csrIdx[4096];     // point index per CSR slot
  __shared__ int offs[NCC + 1];               // CSR starts (exclusive scan)
  __shared__ int cellcnt[NCC];                // counts, then scatter cursor
  __shared__ unsigned int plist[128 * PCAP];  // packed (idx<<12)|pos
  __shared__ int pcnt[128];
  __shared__ unsigned short idxposT[KNN][128];// [slot][query] -> CSR pos
  __shared__ unsigned short embT16[32][128];  // [k][query], bf16

  float2* csrXY = (float2*)smemA;                   // [4096]
  unsigned short(*hs16b)[136] =
      (unsigned short(*)[136])smemA;                // 64 x 136 bf16

  const int t = threadIdx.x;
  const int p = t & 63;                       // lane
  const int q = t >> 6;                       // wave id 0..15, uniform
  const int blk = blockIdx.x;                 // 0..255
  const int b = blk >> 5;                     // batch 0..7
  const int qb = (blk & 31) << 7;             // query base in batch (x128)
  const int bb = b << 12;                     // batch point base (global)
  const int pbase = bb + qb;                  // global query base

  // ---- build 1: load batch points into registers, count cells ----
  float4 Preg[4];
  int cellreg[4];
#pragma unroll
  for (int r = 0; r < 4; ++r) Preg[r] = xytp4[bb + t + 1024 * r];
  if (t < NCC) cellcnt[t] = 0;
  __syncthreads();
#pragma unroll
  for (int r = 0; r < 4; ++r) {
    int cx = min(CG - 1, max(0, (int)(Preg[r].y * (float)CG)));
    int cy = min(CG - 1, max(0, (int)(Preg[r].z * (float)CG)));
    cellreg[r] = cy * CG + cx;
    atomicAdd(&cellcnt[cellreg[r]], 1);
  }
  __syncthreads();

  // ---- build 2: wave 0 exclusive-scans 256 counts (4 cells/lane) ----
  if (q == 0) {
    int b4 = p * 4;
    int s0 = cellcnt[b4], s1 = cellcnt[b4 + 1], s2 = cellcnt[b4 + 2],
        s3 = cellcnt[b4 + 3];
    int tot = s0 + s1 + s2 + s3;
    int inc = tot;
#pragma unroll
    for (int d = 1; d < 64; d <<= 1) {
      int up = __shfl_up(inc, d);
      if (p >= d) inc += up;
    }
    int ex = inc - tot;
    offs[b4] = ex; offs[b4 + 1] = ex + s0;
    offs[b4 + 2] = ex + s0 + s1; offs[b4 + 3] = ex + s0 + s1 + s2;
    if (p == 63) offs[NCC] = inc;
    cellcnt[b4] = ex; cellcnt[b4 + 1] = ex + s0;        // -> cursors
    cellcnt[b4 + 2] = ex + s0 + s1; cellcnt[b4 + 3] = ex + s0 + s1 + s2;
  }
  __syncthreads();

  // ---- build 3: scatter (xy, idx) into CSR (order scrambled) ----
#pragma unroll
  for (int r = 0; r < 4; ++r) {
    int pos = atomicAdd(&cellcnt[cellreg[r]], 1);
    csrXY[pos] = make_float2(Preg[r].y, Preg[r].z);   // one b64 store
    csrIdx[pos] = (unsigned short)(t + 1024 * r);
  }
  __syncthreads();

  // ---- scan: 64 groups of 16 lanes; group gi -> queries gi, gi+64 ----
  {
    const int gi = t >> 4;                    // group 0..63
    const int li = t & 15;                    // lane in group
    const int g = p >> 4;                     // group within wave (ballot)
    const unsigned gbelow = (1u << li) - 1u;
#pragma unroll
    for (int cc = 0; cc < 2; ++cc) {
      int lq = cc * 64 + gi;                  // local query 0..127
      float4 P = xytp4[pbase + lq];           // group-uniform broadcast
      float xn = P.y, yn = P.z;
      float sqn = xn * xn + yn * yn;          // ref sq chain
      int cxlo = max(0, (int)((xn - WIN) * (float)CG));
      int cxhi = min(CG - 1, (int)((xn + WIN) * (float)CG));
      int cylo = max(0, (int)((yn - WIN) * (float)CG));
      int cyhi = min(CG - 1, (int)((yn + WIN) * (float)CG));
      int cnt = 0;
      for (int cy_ = cylo; cy_ <= cyhi; ++cy_)
        for (int cx_ = cxlo; cx_ <= cxhi; ++cx_) {
          int cell = cy_ * CG + cx_;
          int st = offs[cell], en = offs[cell + 1];
          for (int base = st; base < en; base += 16) {
            int e = base + li;
            bool act = e < en;
            int ee = act ? e : st;            // clamp to a valid address
            float2 c2 = csrXY[ee];            // one b64 read
            float cs2 = c2.x * c2.x + c2.y * c2.y;  // == ref sq bits
            float tt = fmaf(yn, c2.y, xn * c2.x);   // ref contracted dot
            float d = (sqn + cs2) - (tt + tt);
            bool pass = act && (d < R2F);
            unsigned long long mask = __ballot(pass);
            unsigned gm = (unsigned)(mask >> (g * 16)) & 0xFFFFu;
            if (pass) {
              int slot = cnt + __popc(gm & gbelow);
              if (slot < PCAP)
                plist[lq * PCAP + slot] =
                    ((unsigned int)csrIdx[ee] << 12) | (unsigned int)ee;
            }
            cnt += __popc(gm);
          }
        }
      if (li == 0) pcnt[lq] = cnt;
    }
  }
  __syncthreads();

  // ---- sort: t<128 sorts packed passers ascending (== by index),
  //      first-16, self-pad with own CSR pos ----
  if (t < 128) {
    int c = min(pcnt[t], PCAP);
    unsigned int* cand = &plist[t * PCAP];
    for (int i = 1; i < c; ++i) {             // insertion sort (c ~ 1-3)
      unsigned int key = cand[i];
      int j = i - 1;
      while (j >= 0 && cand[j] > key) { cand[j + 1] = cand[j]; --j; }
      cand[j + 1] = key;
    }
    unsigned short selfPos = 0;
    if (c < KNN) {                            // self always passes -> found
      unsigned int selfIdx = (unsigned int)(qb + t);
      for (int i = 0; i < c; ++i)
        if ((cand[i] >> 12) == selfIdx) { selfPos = cand[i] & 4095u; break; }
    }
    if (c > KNN) c = KNN;
    for (int k = 0; k < KNN; ++k)
      idxposT[k][t] =
          (k < c) ? (unsigned short)(cand[k] & 4095u) : selfPos;
  }
  __syncthreads();

  // ---- ph3: emb (bf16) for ALL 128 queries, then csrXY dies ----
  {
#pragma unroll
    for (int cc = 0; cc < 2; ++cc) {
      int j = cc * 64 + p;                    // local query
      float4 Pq = xytp4[pbase + j];           // query's raw coords
      int m = idxposT[q][j];                  // CSR pos, q uniform
      float2 M2 = csrXY[m];
      embT16[2 * q][j] = f2bf(Pq.y - M2.x);   // exact f32 sub -> bf16,
      embT16[2 * q + 1][j] = f2bf(Pq.z - M2.y);  // same bits as R18 path
    }
  }
  __syncthreads();                            // csrXY dead after here

  const int lr = p & 15;                      // lane row/col in tile
  const int lg = p >> 4;                      // k-group 0..3

  // ---- MLP: two 64-query chunks (MFMA), hs16b reused ----
#pragma unroll
  for (int cc = 0; cc < 2; ++cc) {
    const int cb = cc * 64;                   // chunk query base
    // ph4 (MFMA): h = emb @ W1 + b1, relu -> bf16 LDS
    {
      const int mi = q & 3;                   // query tile 0..3
      const int ni0 = (q >> 2) * 2;           // unit tiles ni0, ni0+1
      short8 a;
#pragma unroll
      for (int i = 0; i < 8; ++i)
        a[i] = (short)embT16[lg * 8 + i][cb + mi * 16 + lr];
#pragma unroll
      for (int tni = 0; tni < 2; ++tni) {
        const int u0 = (ni0 + tni) * 16;
        short8 bfr;
#pragma unroll
        for (int i = 0; i < 8; ++i)
          bfr[i] = (short)f2bf(W1[(lg * 8 + i) * 128 + u0 + lr]);
        float bs = b1[u0 + lr];
        f32x4 c; c[0] = bs; c[1] = bs; c[2] = bs; c[3] = bs;
        f32x4 d = __builtin_amdgcn_mfma_f32_16x16x32_bf16(a, bfr, c, 0, 0, 0);
#pragma unroll
        for (int j = 0; j < 4; ++j)           // D row = lg*4+j, col = lr
          hs16b[mi * 16 + lg * 4 + j][u0 + lr] = f2bf(fmaxf(d[j], 0.f));
      }
    }
    __syncthreads();

    // ph5 (MFMA): out = relu(h) @ W2 + b2
    {
      const int mi = q >> 2;                  // query tile 0..3
      const int o0 = (q & 3) * 16;            // output tile base
      float bs = b2[o0 + lr];
      f32x4 c; c[0] = bs; c[1] = bs; c[2] = bs; c[3] = bs;
#pragma unroll
      for (int kk = 0; kk < 4; ++kk) {        // K = 128 in 4 steps of 32
        short8 a = *(const short8*)&hs16b[mi * 16 + lr][kk * 32 + lg * 8];
        short8 bfr;
#pragma unroll
        for (int i = 0; i < 8; ++i)
          bfr[i] = (short)f2bf(W2[(kk * 32 + lg * 8 + i) * 64 + o0 + lr]);
        c = __builtin_amdgcn_mfma_f32_16x16x32_bf16(a, bfr, c, 0, 0, 0);
      }
#pragma unroll
      for (int j = 0; j < 4; ++j)             // D row = lg*4+j, col = lr
        out[(size_t)(pbase + cb + mi * 16 + lg * 4 + j) * 64 + o0 + lr] =
            c[j];
    }
    __syncthreads();                          // before next chunk's ph4
  }
}

extern "C" void kernel_launch(void* const* d_in, const int* in_sizes, int n_in,
                              void* d_out, int out_size, void* d_ws, size_t ws_size,
                              hipStream_t stream) {
  const float4* xytp4 = (const float4*)d_in[0];  // [8,4096] (x=ch1, y=ch2)
  const float* W1 = (const float*)d_in[1];
  const float* b1 = (const float*)d_in[2];
  const float* W2 = (const float*)d_in[3];
  const float* b2 = (const float*)d_in[4];
  float* out = (float*)d_out;
  (void)d_ws; (void)ws_size;                  // workspace unused

  hipLaunchKernelGGL(k_all, dim3(256), dim3(1024), 0, stream, xytp4, W1, b1,
                     W2, b2, out);
}

// Round 20
// 76.050 us; speedup vs baseline: 1.0416x; 1.0416x over previous
//
#include <hip/hip_runtime.h>

// Problem constants (fixed by the reference)
#define NB    8
#define NPTS  4096
#define KNN   16
#define CG    16          // coarse cells per axis; cell = 0.0625
#define NCC   (CG * CG)   // 256 cells per batch
#define PCAP  24          // passer cap per query (avg ~1.4; never hit)

// r^2 exactly as the reference: RADIUS = 5.0/480 in f64, squared in f64,
// rounded to f32 by weak promotion in `d2 < radius*radius`.
#define R2F ((float)((5.0 / 480.0) * (5.0 / 480.0)))
#define WIN 0.011f

typedef short short8 __attribute__((ext_vector_type(8)));
typedef float f32x4 __attribute__((ext_vector_type(4)));

// f32 -> bf16 round-to-nearest-even (top 16 bits after rounding).
static __device__ __forceinline__ unsigned short f2bf(float f) {
  unsigned u = __float_as_uint(f);
  u += 0x7FFFu + ((u >> 16) & 1u);
  return (unsigned short)(u >> 16);
}

// ---------------------------------------------------------------------------
// K_all: R18 CHAMPION, reverted to after R19's occupancy experiment
// regressed (256 blocks x 128 queries = 1 block/CU: build savings < lost
// phase-overlap between co-resident blocks; +2.4us). This structure is at
// its measured floor: payload 14.2us = ramp ~5 + build ~4 (R14 split and
// R19 halving both worse) + scan ~1 + sort/ph3 ~1 + MFMA ~1 + writes ~1,
// against a 62.65us fixed harness floor (fill train at 80% HBM).
//   build: per-block LDS CSR (count -> wave-0 prefix -> scatter).
//   scan: one query per 16-lane group (4/wave); ballot-ordered append;
//         bit-exact ref fp32 chain (sq / fmaf dot / (sqn+cs2)-(tt+tt)).
//   sort: packed (idx<<12)|pos ascending == by-index; first-16; self-pad.
//   ph3:  emb = exact f32 subs from LDS CSR.
//   ph4/ph5 (MFMA 16x16x32 bf16): h = relu(emb@W1+b1) -> bf16 LDS
//         hs16b[64][136]; out = relu(h)@W2 + b2, f32 acc b2-seeded.
//         absmax 6.103516e-05, 4x inside the 2.4e-4 gate.
// Fragment layouts (gfx950): A[l&15][(l>>4)*8+i], B[(l>>4)*8+i][l&15],
// D col=l&15 row=(l>>4)*4+j (guide m89-verified).
// ---------------------------------------------------------------------------
__global__ __launch_bounds__(1024, 8) void k_all(
    const float4* __restrict__ xytp4, const float* __restrict__ W1,
    const float* __restrict__ b1, const float* __restrict__ W2,
    const float* __restrict__ b2, float* __restrict__ out) {
#pragma clang fp contract(off)
  // Region A (32KB): csrX[4096]+csrY[4096] -> hs16b[64][136] after ph3.
  __shared__ __align__(16) char smemA[32768];
  __shared__ unsigned short csrIdx[4096];     // point index per CSR slot
  __shared__ int offs[NCC + 1];               // CSR starts (exclusive scan)
  __shared__ int cellcnt[NCC];                // counts, then scatter cursor
  __shared__ unsigned int plist[64 * PCAP];   // packed (idx<<12)|pos
  __shared__ int pcnt[64];
  __shared__ unsigned short idxposT[KNN][64]; // [slot][query] -> CSR pos
  __shared__ float embT[32][64];              // [k][query]

  float* csrX = (float*)smemA;                      // [4096]
  float* csrY = (float*)(smemA + 16384);            // [4096]
  unsigned short(*hs16b)[136] =
      (unsigned short(*)[136])smemA;                // 64 x 136 bf16

  const int t = threadIdx.x;
  const int p = t & 63;                       // lane
  const int q = t >> 6;                       // wave id 0..15, uniform
  const int pbase = blockIdx.x * 64;          // global query base
  const int bb = pbase & ~4095;               // batch point base (global)
  const int lqbase = pbase & 4095;            // batch-local query base

  // ---- build 1: load batch points into registers, count cells ----
  float4 Preg[4];
  int cellreg[4];
#pragma unroll
  for (int r = 0; r < 4; ++r) Preg[r] = xytp4[bb + t + 1024 * r];
  if (t < NCC) cellcnt[t] = 0;
  __syncthreads();
#pragma unroll
  for (int r = 0; r < 4; ++r) {
    int cx = min(CG - 1, max(0, (int)(Preg[r].y * (float)CG)));
    int cy = min(CG - 1, max(0, (int)(Preg[r].z * (float)CG)));
    cellreg[r] = cy * CG + cx;
    atomicAdd(&cellcnt[cellreg[r]], 1);
  }
  __syncthreads();

  // ---- build 2: wave 0 exclusive-scans 256 counts (4 cells/lane) ----
  if (q == 0) {
    int b4 = p * 4;
    int s0 = cellcnt[b4], s1 = cellcnt[b4 + 1], s2 = cellcnt[b4 + 2],
        s3 = cellcnt[b4 + 3];
    int tot = s0 + s1 + s2 + s3;
    int inc = tot;
#pragma unroll
    for (int d = 1; d < 64; d <<= 1) {
      int up = __shfl_up(inc, d);
      if (p >= d) inc += up;
    }
    int ex = inc - tot;
    offs[b4] = ex; offs[b4 + 1] = ex + s0;
    offs[b4 + 2] = ex + s0 + s1; offs[b4 + 3] = ex + s0 + s1 + s2;
    if (p == 63) offs[NCC] = inc;
    cellcnt[b4] = ex; cellcnt[b4 + 1] = ex + s0;        // -> cursors
    cellcnt[b4 + 2] = ex + s0 + s1; cellcnt[b4 + 3] = ex + s0 + s1 + s2;
  }
  __syncthreads();

  // ---- build 3: scatter (x, y, idx) into CSR (order scrambled) ----
#pragma unroll
  for (int r = 0; r < 4; ++r) {
    int pos = atomicAdd(&cellcnt[cellreg[r]], 1);
    csrX[pos] = Preg[r].y; csrY[pos] = Preg[r].z;
    csrIdx[pos] = (unsigned short)(t + 1024 * r);
  }
  __syncthreads();

  // ---- scan: one query per 16-lane group (4 concurrent per wave) ----
  {
    const int g = p >> 4;                     // group 0..3
    const int li = p & 15;                    // lane in group
    const int lq = q * 4 + g;                 // this group's query
    const unsigned gbelow = (1u << li) - 1u;
    float4 P = xytp4[pbase + lq];             // group-uniform broadcast
    float xn = P.y, yn = P.z;
    float sqn = xn * xn + yn * yn;            // ref sq chain
    int cxlo = max(0, (int)((xn - WIN) * (float)CG));
    int cxhi = min(CG - 1, (int)((xn + WIN) * (float)CG));
    int cylo = max(0, (int)((yn - WIN) * (float)CG));
    int cyhi = min(CG - 1, (int)((yn + WIN) * (float)CG));
    int cnt = 0;
    for (int cy_ = cylo; cy_ <= cyhi; ++cy_)
      for (int cx_ = cxlo; cx_ <= cxhi; ++cx_) {
        int cell = cy_ * CG + cx_;
        int st = offs[cell], en = offs[cell + 1];
        for (int base = st; base < en; base += 16) {
          int e = base + li;
          bool act = e < en;
          int ee = act ? e : st;              // clamp to a valid address
          float cx2 = csrX[ee], cy2 = csrY[ee];
          float cs2 = cx2 * cx2 + cy2 * cy2;  // == ref sq bits
          float tt = fmaf(yn, cy2, xn * cx2); // ref contracted dot
          float d = (sqn + cs2) - (tt + tt);
          bool pass = act && (d < R2F);
          unsigned long long mask = __ballot(pass);
          unsigned gm = (unsigned)(mask >> (g * 16)) & 0xFFFFu;
          if (pass) {
            int slot = cnt + __popc(gm & gbelow);
            if (slot < PCAP)
              plist[lq * PCAP + slot] =
                  ((unsigned int)csrIdx[ee] << 12) | (unsigned int)ee;
          }
          cnt += __popc(gm);
        }
      }
    if (li == 0) pcnt[lq] = cnt;
  }
  __syncthreads();

  // ---- sort: t<64 sorts packed passers ascending (== by index),
  //      first-16, self-pad with own CSR pos ----
  if (t < 64) {
    int c = min(pcnt[t], PCAP);
    unsigned int* cand = &plist[t * PCAP];
    for (int i = 1; i < c; ++i) {             // insertion sort (c ~ 1-3)
      unsigned int key = cand[i];
      int j = i - 1;
      while (j >= 0 && cand[j] > key) { cand[j + 1] = cand[j]; --j; }
      cand[j + 1] = key;
    }
    unsigned short selfPos = 0;
    if (c < KNN) {                            // self always passes -> found
      unsigned int selfIdx = (unsigned int)(lqbase + t);
      for (int i = 0; i < c; ++i)
        if ((cand[i] >> 12) == selfIdx) { selfPos = cand[i] & 4095u; break; }
    }
    if (c > KNN) c = KNN;
    for (int k = 0; k < KNN; ++k)
      idxposT[k][t] =
          (k < c) ? (unsigned short)(cand[k] & 4095u) : selfPos;
  }
  __syncthreads();

  // ---- ph3: emb from LDS CSR (wave q = slot q of every query) ----
  {
    float4 Pq = xytp4[pbase + p];             // query p's raw coords
    int m = idxposT[q][p];                    // CSR pos, q uniform
    embT[2 * q][p] = Pq.y - csrX[m];          // exact fp32 sub, same bits
    embT[2 * q + 1][p] = Pq.z - csrY[m];      // bank p%32: conflict-free
  }
  __syncthreads();                            // csrX/csrY dead after here

  const int lr = p & 15;                      // lane row/col in tile
  const int lg = p >> 4;                      // k-group 0..3

  // ---- ph4 (MFMA): h = emb @ W1 + b1, relu -> bf16 LDS ----
  {
    const int mi = q & 3;                     // query tile 0..3
    const int ni0 = (q >> 2) * 2;             // unit tiles ni0, ni0+1
    // A-frag (shared by both tiles): emb[mi*16+lr][lg*8+i]
    short8 a;
#pragma unroll
    for (int i = 0; i < 8; ++i)
      a[i] = (short)f2bf(embT[lg * 8 + i][mi * 16 + lr]);
#pragma unroll
    for (int tni = 0; tni < 2; ++tni) {
      const int u0 = (ni0 + tni) * 16;
      short8 bfr;
#pragma unroll
      for (int i = 0; i < 8; ++i)
        bfr[i] = (short)f2bf(W1[(lg * 8 + i) * 128 + u0 + lr]);
      float bs = b1[u0 + lr];
      f32x4 c; c[0] = bs; c[1] = bs; c[2] = bs; c[3] = bs;
      f32x4 d = __builtin_amdgcn_mfma_f32_16x16x32_bf16(a, bfr, c, 0, 0, 0);
#pragma unroll
      for (int j = 0; j < 4; ++j)             // D row = lg*4+j, col = lr
        hs16b[mi * 16 + lg * 4 + j][u0 + lr] = f2bf(fmaxf(d[j], 0.f));
    }
  }
  __syncthreads();

  // ---- ph5 (MFMA): out = relu(h) @ W2 + b2 ----
  {
    const int mi = q >> 2;                    // query tile 0..3
    const int o0 = (q & 3) * 16;              // output tile base
    float bs = b2[o0 + lr];
    f32x4 c; c[0] = bs; c[1] = bs; c[2] = bs; c[3] = bs;
#pragma unroll
    for (int kk = 0; kk < 4; ++kk) {          // K = 128 in 4 steps of 32
      // A: h[mi*16+lr][kk*32 + lg*8 .. +8] -- one 16B LDS read
      short8 a = *(const short8*)&hs16b[mi * 16 + lr][kk * 32 + lg * 8];
      short8 bfr;
#pragma unroll
      for (int i = 0; i < 8; ++i)
        bfr[i] = (short)f2bf(W2[(kk * 32 + lg * 8 + i) * 64 + o0 + lr]);
      c = __builtin_amdgcn_mfma_f32_16x16x32_bf16(a, bfr, c, 0, 0, 0);
    }
#pragma unroll
    for (int j = 0; j < 4; ++j)               // D row = lg*4+j, col = lr
      out[(size_t)(pbase + mi * 16 + lg * 4 + j) * 64 + o0 + lr] = c[j];
  }
}

extern "C" void kernel_launch(void* const* d_in, const int* in_sizes, int n_in,
                              void* d_out, int out_size, void* d_ws, size_t ws_size,
                              hipStream_t stream) {
  const float4* xytp4 = (const float4*)d_in[0];  // [8,4096] (x=ch1, y=ch2)
  const float* W1 = (const float*)d_in[1];
  const float* b1 = (const float*)d_in[2];
  const float* W2 = (const float*)d_in[3];
  const float* b2 = (const float*)d_in[4];
  float* out = (float*)d_out;
  (void)d_ws; (void)ws_size;                  // workspace unused

  hipLaunchKernelGGL(k_all, dim3(512), dim3(1024), 0, stream, xytp4, W1, b1,
                     W2, b2, out);
}